// Round 13
// baseline (462.448 us; speedup 1.0000x reference)
//
#include <hip/hip_runtime.h>

#define BB 8
#define CC 64
#define OO 128
#define NN 4096
#define KNN 20
#define NT 256          // 16-j tiles per batch scan
#define NG 64           // 4-tile groups
#define RING 9          // per-lane LDS ring slots
#define TRIG 5          // drain when any lane cnt>=5 (growth <=4/tile -> <=8)
#define SPLITW 192      // xsp row: 64 bf16 h | 64 bf16 m | 64 bf16 l (384 B)
#define WSPL 384        // Wsp row: 128 bf16 h | 128 m | 128 l (768 B)
#define TILEB (16 * SPLITW * 2)  // 6144 B per 16-row B tile

typedef short bf16x8 __attribute__((ext_vector_type(8)));
typedef float f32x4 __attribute__((ext_vector_type(4)));
typedef const __attribute__((address_space(1))) unsigned int* gas_ptr;
typedef __attribute__((address_space(3))) unsigned int* las_ptr;

// ===========================================================================
// knn ledger: R17 barrier-lockstep main loop = ~349us (VERBATIM; 5 structural
// attacks regressed; 2-blocks/CU pinned by grid x LDS-granularity).
// R22 precompute split / R23 MFMA precompute / R26-R27 fused branch-free
// merge tail / R30 fused A/Q pass: total 688 -> 447.8us.
// R31: wsplit folded into xprep block (0,0) -- kills the standalone dispatch
//   + launch gap (~6-8us). W row loads coalesced; Wsp->knn ordering still
//   guaranteed by stream serialization (xprep precedes knn).
// Note: R30 showed one 30.8ms profiling outlier (FETCH 125GB-u) with clean
// typical dispatches -- watching; no steady-state spill indicators.
// ===========================================================================
#define REP20(F, P) F(P,0) F(P,1) F(P,2) F(P,3) F(P,4) F(P,5) F(P,6) F(P,7) \
    F(P,8) F(P,9) F(P,10) F(P,11) F(P,12) F(P,13) F(P,14) F(P,15) F(P,16)   \
    F(P,17) F(P,18) F(P,19)

#define TS_DECL(P,k) float P##m##k = 1e30f; int P##p##k = -1;
#define TS_REPL(P,k)                                                        \
  { const bool _h = (P##kpos == (k));                                       \
    P##m##k = _h ? _d : P##m##k;                                            \
    P##p##k = _h ? _j : P##p##k; }

#define TS_N(vd, xd, va, xa, vb, xb)                                        \
  { const bool _g = (vb) > (va); vd = _g ? (vb) : (va); xd = _g ? (xb) : (xa); }

#define TS_TREE(P)                                                          \
  { float t0,t1,t2,t3,t4,t5,t6,t7,t8,t9; int y0,y1,y2,y3,y4,y5,y6,y7,y8,y9; \
    TS_N(t0,y0, P##m0,0,  P##m1,1)   TS_N(t1,y1, P##m2,2,  P##m3,3)         \
    TS_N(t2,y2, P##m4,4,  P##m5,5)   TS_N(t3,y3, P##m6,6,  P##m7,7)         \
    TS_N(t4,y4, P##m8,8,  P##m9,9)   TS_N(t5,y5, P##m10,10, P##m11,11)      \
    TS_N(t6,y6, P##m12,12, P##m13,13) TS_N(t7,y7, P##m14,14, P##m15,15)     \
    TS_N(t8,y8, P##m16,16, P##m17,17) TS_N(t9,y9, P##m18,18, P##m19,19)     \
    float u0,u1,u2,u3,u4; int z0,z1,z2,z3,z4;                               \
    TS_N(u0,z0, t0,y0, t1,y1) TS_N(u1,z1, t2,y2, t3,y3)                     \
    TS_N(u2,z2, t4,y4, t5,y5) TS_N(u3,z3, t6,y6, t7,y7)                     \
    TS_N(u4,z4, t8,y8, t9,y9)                                               \
    float w0,w1; int q0,q1;                                                 \
    TS_N(w0,q0, u0,z0, u1,z1) TS_N(w1,q1, u2,z2, u3,z3)                     \
    float e0; int r0;                                                       \
    TS_N(e0,r0, w0,q0, w1,q1)                                               \
    TS_N(P##kmax, P##kpos, e0,r0, u4,z4) }

#define TS_INS(P, dval, jval)                                               \
  { const float _d = (dval); const int _j = (jval);                         \
    REP20(TS_REPL, P)                                                       \
    TS_TREE(P) }

// row-threshold refresh: rt = min(kmax over the 4 lanes sharing myrow)
#define RT_UPDATE                                                           \
  { const int _s1 = __builtin_amdgcn_ds_swizzle(__float_as_int(A_kmax), 0x101F); \
    const float _m1 = fminf(A_kmax, __int_as_float(_s1));                   \
    const int _s2 = __builtin_amdgcn_ds_swizzle(__float_as_int(_m1), 0x201F); \
    rt = fminf(_m1, __int_as_float(_s2)); }

// ---- branch-free lex compare-swap on A_ slots (ascending) ----
#define MSW(a, b)                                                           \
  { const bool _s = (A_m##b < A_m##a) ||                                    \
                    ((A_m##b == A_m##a) && (A_p##b < A_p##a));              \
    const float _fa = _s ? A_m##b : A_m##a;                                 \
    const float _fb = _s ? A_m##a : A_m##b;                                 \
    const int _ia = _s ? A_p##b : A_p##a;                                   \
    const int _ib = _s ? A_p##a : A_p##b;                                   \
    A_m##a = _fa; A_m##b = _fb; A_p##a = _ia; A_p##b = _ib; }

#define SRND_E MSW(0,1) MSW(2,3) MSW(4,5) MSW(6,7) MSW(8,9) MSW(10,11)      \
    MSW(12,13) MSW(14,15) MSW(16,17) MSW(18,19)
#define SRND_O MSW(1,2) MSW(3,4) MSW(5,6) MSW(7,8) MSW(9,10) MSW(11,12)     \
    MSW(13,14) MSW(15,16) MSW(17,18)
// odd-even transposition sort: 20 rounds suffice for 20 elements
#define SORT20 SRND_E SRND_O SRND_E SRND_O SRND_E SRND_O SRND_E SRND_O      \
    SRND_E SRND_O SRND_E SRND_O SRND_E SRND_O SRND_E SRND_O SRND_E SRND_O  \
    SRND_E SRND_O

__device__ __forceinline__ unsigned rne_bf16(float f) {
  const unsigned u = __float_as_uint(f);
  return (u + 0x7fffu + ((u >> 16) & 1u)) >> 16;
}

// ---------------------------------------------------------------------------
// Kernel 1: per-point xsq + 3-split xsp; block (0,0) also splits W -> Wsp
// (R31: folded wsplit — one row per iteration, coalesced row loads).
// ---------------------------------------------------------------------------
__global__ __launch_bounds__(128, 3) void xprep_kernel(
    const float* __restrict__ x, const float* __restrict__ W,
    float* __restrict__ xsq, unsigned short* __restrict__ xsp,
    unsigned short* __restrict__ Wsp) {
  const int b = blockIdx.y;
  const int n = blockIdx.x * 128 + threadIdx.x;

  if (blockIdx.x == 0 && b == 0) {
    const int t = threadIdx.x;  // column
    for (int o = 0; o < OO; ++o) {
      const float w = W[(size_t)o * (2 * CC) + t];
      const unsigned h = rne_bf16(w);
      const float r = w - __uint_as_float(h << 16);
      const unsigned m = rne_bf16(r);
      const float s = r - __uint_as_float(m << 16);
      const unsigned l = rne_bf16(s);
      unsigned short* row = Wsp + (size_t)o * WSPL;
      row[t] = (unsigned short)h;
      row[128 + t] = (unsigned short)m;
      row[256 + t] = (unsigned short)l;
    }
  }

  const float* xb = x + (size_t)b * CC * NN;

  float xr[CC];
  float sq = 0.f;
#pragma unroll
  for (int c = 0; c < CC; ++c) {
    xr[c] = xb[(size_t)c * NN + n];
    sq = fmaf(xr[c], xr[c], sq);
  }
  xsq[(size_t)b * NN + n] = sq;

  unsigned* srow = (unsigned*)(xsp + ((size_t)b * NN + n) * SPLITW);
#pragma unroll
  for (int c = 0; c < CC; c += 2) {
    const unsigned h0 = rne_bf16(xr[c]), h1 = rne_bf16(xr[c + 1]);
    const float r0 = xr[c] - __uint_as_float(h0 << 16);
    const float r1 = xr[c + 1] - __uint_as_float(h1 << 16);
    const unsigned m0 = rne_bf16(r0), m1 = rne_bf16(r1);
    const float s0 = r0 - __uint_as_float(m0 << 16);
    const float s1 = r1 - __uint_as_float(m1 << 16);
    const unsigned l0 = rne_bf16(s0), l1 = rne_bf16(s1);
    srow[c / 2] = h0 | (h1 << 16);
    srow[32 + c / 2] = m0 | (m1 << 16);
    srow[64 + c / 2] = l0 | (l1 << 16);
  }
}

// ---------------------------------------------------------------------------
// 3-split 6-product MFMA (proven pattern; used by knn tiles and fused A/Q).
// ---------------------------------------------------------------------------
#define MFMA6(ACC, B0, B1, B2, B3, B4, B5)                                  \
  f32x4 ACC;                                                                \
  { f32x4 a0 = {0.f,0.f,0.f,0.f}; f32x4 a1 = {0.f,0.f,0.f,0.f};             \
    f32x4 a2 = {0.f,0.f,0.f,0.f}; f32x4 a3 = {0.f,0.f,0.f,0.f};             \
    a0 = __builtin_amdgcn_mfma_f32_16x16x32_bf16(Ah0, B0, a0, 0, 0, 0);     \
    a1 = __builtin_amdgcn_mfma_f32_16x16x32_bf16(Ah1, B1, a1, 0, 0, 0);     \
    a2 = __builtin_amdgcn_mfma_f32_16x16x32_bf16(Ah0, B2, a2, 0, 0, 0);     \
    a3 = __builtin_amdgcn_mfma_f32_16x16x32_bf16(Ah1, B3, a3, 0, 0, 0);     \
    a0 = __builtin_amdgcn_mfma_f32_16x16x32_bf16(Am0, B0, a0, 0, 0, 0);     \
    a1 = __builtin_amdgcn_mfma_f32_16x16x32_bf16(Am1, B1, a1, 0, 0, 0);     \
    a2 = __builtin_amdgcn_mfma_f32_16x16x32_bf16(Ah0, B4, a2, 0, 0, 0);     \
    a3 = __builtin_amdgcn_mfma_f32_16x16x32_bf16(Ah1, B5, a3, 0, 0, 0);     \
    a0 = __builtin_amdgcn_mfma_f32_16x16x32_bf16(Al0, B0, a0, 0, 0, 0);     \
    a1 = __builtin_amdgcn_mfma_f32_16x16x32_bf16(Al1, B1, a1, 0, 0, 0);     \
    a2 = __builtin_amdgcn_mfma_f32_16x16x32_bf16(Am0, B2, a2, 0, 0, 0);     \
    a3 = __builtin_amdgcn_mfma_f32_16x16x32_bf16(Am1, B3, a3, 0, 0, 0);     \
    ACC = (a0 + a1) + (a2 + a3); }

// ---------------------------------------------------------------------------
// Kernel 2: MFMA Gram-matrix kNN (main loop = R17 VERBATIM).
// Tail: sort+4-way merge (R27) then fused A/Q pass (R30).
// ---------------------------------------------------------------------------
#define STAGEG(G, BUF)                                                      \
  { const char* tb = (const char*)xspB + (size_t)(4 * (G) + wv) * TILEB + gof; \
    char* lb = (char*)(BUF) + wv * 6144;                                    \
    __builtin_amdgcn_global_load_lds((gas_ptr)(const void*)(tb), (las_ptr)(void*)(lb), 16, 0, 0); \
    __builtin_amdgcn_global_load_lds((gas_ptr)(const void*)(tb + 64), (las_ptr)(void*)(lb + 1024), 16, 0, 0); \
    __builtin_amdgcn_global_load_lds((gas_ptr)(const void*)(tb + 128), (las_ptr)(void*)(lb + 2048), 16, 0, 0); \
    __builtin_amdgcn_global_load_lds((gas_ptr)(const void*)(tb + 192), (las_ptr)(void*)(lb + 3072), 16, 0, 0); \
    __builtin_amdgcn_global_load_lds((gas_ptr)(const void*)(tb + 256), (las_ptr)(void*)(lb + 4096), 16, 0, 0); \
    __builtin_amdgcn_global_load_lds((gas_ptr)(const void*)(tb + 320), (las_ptr)(void*)(lb + 5120), 16, 0, 0); }

#define TILE_MFMA_L(LBUF, BUF)                                              \
  { const char* bb = (const char*)(LBUF) + c16;                             \
    const bf16x8 Bh0 = *(const bf16x8*)(bb + (q + 0) * 256);                \
    const bf16x8 Bh1 = *(const bf16x8*)(bb + (q + 4) * 256);                \
    const bf16x8 Bm0 = *(const bf16x8*)(bb + (q + 8) * 256);                \
    const bf16x8 Bm1 = *(const bf16x8*)(bb + (q + 12) * 256);               \
    const bf16x8 Bl0 = *(const bf16x8*)(bb + (q + 16) * 256);               \
    const bf16x8 Bl1 = *(const bf16x8*)(bb + (q + 20) * 256);               \
    f32x4 ac0 = {0.f, 0.f, 0.f, 0.f};                                       \
    f32x4 ac1 = {0.f, 0.f, 0.f, 0.f};                                       \
    f32x4 ac2 = {0.f, 0.f, 0.f, 0.f};                                       \
    f32x4 ac3 = {0.f, 0.f, 0.f, 0.f};                                       \
    ac0 = __builtin_amdgcn_mfma_f32_16x16x32_bf16(Ah0, Bh0, ac0, 0, 0, 0);  \
    ac1 = __builtin_amdgcn_mfma_f32_16x16x32_bf16(Ah1, Bh1, ac1, 0, 0, 0);  \
    ac2 = __builtin_amdgcn_mfma_f32_16x16x32_bf16(Ah0, Bm0, ac2, 0, 0, 0);  \
    ac3 = __builtin_amdgcn_mfma_f32_16x16x32_bf16(Ah1, Bm1, ac3, 0, 0, 0);  \
    ac0 = __builtin_amdgcn_mfma_f32_16x16x32_bf16(Am0, Bh0, ac0, 0, 0, 0);  \
    ac1 = __builtin_amdgcn_mfma_f32_16x16x32_bf16(Am1, Bh1, ac1, 0, 0, 0);  \
    ac2 = __builtin_amdgcn_mfma_f32_16x16x32_bf16(Ah0, Bl0, ac2, 0, 0, 0);  \
    ac3 = __builtin_amdgcn_mfma_f32_16x16x32_bf16(Ah1, Bl1, ac3, 0, 0, 0);  \
    ac0 = __builtin_amdgcn_mfma_f32_16x16x32_bf16(Al0, Bh0, ac0, 0, 0, 0);  \
    ac1 = __builtin_amdgcn_mfma_f32_16x16x32_bf16(Al1, Bh1, ac1, 0, 0, 0);  \
    ac2 = __builtin_amdgcn_mfma_f32_16x16x32_bf16(Am0, Bm0, ac2, 0, 0, 0);  \
    ac3 = __builtin_amdgcn_mfma_f32_16x16x32_bf16(Am1, Bm1, ac3, 0, 0, 0);  \
    const f32x4 acc = (ac0 + ac1) + (ac2 + ac3);                            \
    float* bw = &bounce[BUF][wv][0];                                        \
    bw[(q * 4 + 0) * 20 + c] = acc[0];                                      \
    bw[(q * 4 + 1) * 20 + c] = acc[1];                                      \
    bw[(q * 4 + 2) * 20 + c] = acc[2];                                      \
    bw[(q * 4 + 3) * 20 + c] = acc[3]; }

#define TILE_VALS(T, BUF)                                                   \
  const float* br = &bounce[BUF][wv][myrow * 20 + 4 * g];                   \
  const f32x4 dots = *(const f32x4*)br;                                     \
  const float4 xx = *(const float4*)(xsqb + (T) * 16 + 4 * g);              \
  const float d0 = fmaf(-2.f, dots[0], xx.x);                               \
  const float d1 = fmaf(-2.f, dots[1], xx.y);                               \
  const float d2 = fmaf(-2.f, dots[2], xx.z);                               \
  const float d3 = fmaf(-2.f, dots[3], xx.w);                               \
  const int jb = (T) * 16 + 4 * g;

#define TILE_SELF(T, BUF, K0, K1, K2, K3)                                   \
  { TILE_VALS(T, BUF)                                                       \
    A_m##K0 = d0; A_p##K0 = jb;                                             \
    A_m##K1 = d1; A_p##K1 = jb + 1;                                         \
    A_m##K2 = d2; A_p##K2 = jb + 2;                                         \
    A_m##K3 = d3; A_p##K3 = jb + 3; }

#define TILE_SEL(T, BUF)                                                    \
  { TILE_VALS(T, BUF)                                                       \
    if (d0 <= rt) { myring[cnt] = make_float2(d0, __int_as_float(jb)); ++cnt; } \
    if (d1 <= rt) { myring[cnt] = make_float2(d1, __int_as_float(jb + 1)); ++cnt; } \
    if (d2 <= rt) { myring[cnt] = make_float2(d2, __int_as_float(jb + 2)); ++cnt; } \
    if (d3 <= rt) { myring[cnt] = make_float2(d3, __int_as_float(jb + 3)); ++cnt; } \
    if (__ballot(cnt >= TRIG)) {                                            \
      for (int _k = 0; _k < cnt; ++_k) {                                    \
        const float2 e = myring[_k];                                        \
        if (e.x < A_kmax) { TS_INS(A_, e.x, __float_as_int(e.y)) }          \
      }                                                                     \
      cnt = 0;                                                              \
    }                                                                       \
    RT_UPDATE }

__global__ __launch_bounds__(256, 2) void knn_kernel(
    const unsigned short* __restrict__ xsp, const float* __restrict__ xsq,
    const unsigned short* __restrict__ Wsp, const float* __restrict__ bias,
    unsigned short* __restrict__ Ab16, float* __restrict__ Q,
    int* __restrict__ idxf) {
  __shared__ unsigned short Bbuf0[4 * TILEB / 2];  // 24 KB (even groups)
  __shared__ unsigned short Bbuf1[4 * TILEB / 2];  // 24 KB (odd groups)
  __shared__ float bounce[2][4][16 * 20];          // 10 KB
  __shared__ float2 ring[256][RING];               // 18 KB

  const int b = blockIdx.y;
  const int wv = threadIdx.x >> 6;
  const int lane = threadIdx.x & 63;
  const int q = lane >> 4;
  const int c = lane & 15;
  const int c16 = c * 16;
  const int gof = c * 384 + q * 16;  // staging source offset (k adds 64)
  const int ibase = blockIdx.x * 64 + wv * 16;
  const int myrow = q * 4 + (c & 3);
  const int g = c >> 2;
  const int isel = ibase + myrow;

  const unsigned short* xspB = xsp + (size_t)b * NN * SPLITW;
  const float* xsqb = xsq + (size_t)b * NN;

  // A fragments: rows ibase+c, k-slice quad*8 (+32 for k-chunk 1)
  const unsigned short* arow = xspB + (size_t)(ibase + c) * SPLITW + q * 8;
  const bf16x8 Ah0 = *(const bf16x8*)(arow);
  const bf16x8 Ah1 = *(const bf16x8*)(arow + 32);
  const bf16x8 Am0 = *(const bf16x8*)(arow + 64);
  const bf16x8 Am1 = *(const bf16x8*)(arow + 96);
  const bf16x8 Al0 = *(const bf16x8*)(arow + 128);
  const bf16x8 Al1 = *(const bf16x8*)(arow + 160);

  REP20(TS_DECL, A_)
  float A_kmax = 1e30f; int A_kpos = 0;
  float rt = 1e30f;
  float2* myring = ring[threadIdx.x];
  int cnt = 0;

  // ---- prologue ----
  STAGEG(0, Bbuf0)
  __syncthreads();
  STAGEG(1, Bbuf1)
  TILE_MFMA_L(Bbuf0 + 0 * 3072, 0)
  TILE_MFMA_L(Bbuf0 + 1 * 3072, 1) TILE_SELF(0, 0, 0, 1, 2, 3)
  TILE_MFMA_L(Bbuf0 + 2 * 3072, 0) TILE_SELF(1, 1, 4, 5, 6, 7)
  TILE_MFMA_L(Bbuf0 + 3 * 3072, 1) TILE_SELF(2, 0, 8, 9, 10, 11)
  __syncthreads();
  STAGEG(2, Bbuf0)
  TILE_MFMA_L(Bbuf1 + 0 * 3072, 0) TILE_SELF(3, 1, 12, 13, 14, 15)
  TILE_MFMA_L(Bbuf1 + 1 * 3072, 1) TILE_SELF(4, 0, 16, 17, 18, 19)
  TS_TREE(A_)
  RT_UPDATE
  TILE_MFMA_L(Bbuf1 + 2 * 3072, 0) TILE_SEL(5, 1)
  TILE_MFMA_L(Bbuf1 + 3 * 3072, 1) TILE_SEL(6, 0)
  __syncthreads();

  // ---- steady state: groups 2..62 ----
  for (int G = 2; G < NG - 1; ++G) {
    unsigned short* cur = (G & 1) ? Bbuf1 : Bbuf0;
    unsigned short* nxt = (G & 1) ? Bbuf0 : Bbuf1;
    STAGEG(G + 1, nxt)
    const int t0 = 4 * G;
    TILE_MFMA_L(cur + 0 * 3072, 0) TILE_SEL(t0 - 1, 1)
    TILE_MFMA_L(cur + 1 * 3072, 1) TILE_SEL(t0, 0)
    TILE_MFMA_L(cur + 2 * 3072, 0) TILE_SEL(t0 + 1, 1)
    TILE_MFMA_L(cur + 3 * 3072, 1) TILE_SEL(t0 + 2, 0)
    __syncthreads();
  }

  // ---- epilogue: group 63 (tiles 252..255 in Bbuf1), no staging ----
  TILE_MFMA_L(Bbuf1 + 0 * 3072, 0) TILE_SEL(251, 1)
  TILE_MFMA_L(Bbuf1 + 1 * 3072, 1) TILE_SEL(252, 0)
  TILE_MFMA_L(Bbuf1 + 2 * 3072, 0) TILE_SEL(253, 1)
  TILE_MFMA_L(Bbuf1 + 3 * 3072, 1) TILE_SEL(254, 0)
  TILE_SEL(255, 1)

  // final drain
  for (int _k = 0; _k < cnt; ++_k) {
    const float2 e = myring[_k];
    if (e.x < A_kmax) { TS_INS(A_, e.x, __float_as_int(e.y)) }
  }

  // ---- R27 tail: branch-free sort + 4-way sorted merge ----
  __syncthreads();
  {
    SORT20
    float2* dumpw = (float2*)((wv & 2) ? (char*)Bbuf1 + (wv & 1) * 10752
                                       : (char*)Bbuf0 + (wv & 1) * 10752);
    float2* mydump = dumpw + lane * 21;
#define MG_DUMP(P, k) mydump[k] = make_float2(P##m##k, __int_as_float(P##p##k));
    REP20(MG_DUMP, A_)
#undef MG_DUMP
    const int srow = q * 16 + (c & 3);
    const float2* l0 = dumpw + (size_t)(srow + 0) * 21;
    const float2* l1 = dumpw + (size_t)(srow + 4) * 21;
    const float2* l2 = dumpw + (size_t)(srow + 8) * 21;
    const float2* l3 = dumpw + (size_t)(srow + 12) * 21;
    int c0 = 0, c1 = 0, c2 = 0, c3 = 0;
    float2 h0 = l0[0], h1 = l1[0], h2 = l2[0], h3 = l3[0];
    const size_t obase = (size_t)b * KNN * NN + isel;
    for (int k = 0; k < KNN; ++k) {
      const bool s01 =
          (h1.x < h0.x) ||
          ((h1.x == h0.x) && (__float_as_int(h1.y) < __float_as_int(h0.y)));
      const float2 m01 = s01 ? h1 : h0;
      const bool s23 =
          (h3.x < h2.x) ||
          ((h3.x == h2.x) && (__float_as_int(h3.y) < __float_as_int(h2.y)));
      const float2 m23 = s23 ? h3 : h2;
      const bool sF =
          (m23.x < m01.x) ||
          ((m23.x == m01.x) && (__float_as_int(m23.y) < __float_as_int(m01.y)));
      const float2 mm = sF ? m23 : m01;
      if (g == 0) idxf[obase + (size_t)k * NN] = __float_as_int(mm.y);
      const int w = sF ? (s23 ? 3 : 2) : (s01 ? 1 : 0);
      c0 += (w == 0); c1 += (w == 1); c2 += (w == 2); c3 += (w == 3);
      const float2 n0 = l0[c0], n1 = l1[c1], n2 = l2[c2], n3 = l3[c3];
      const float2 inf2 = make_float2(1e30f, __int_as_float(0x7fffffff));
      h0 = (c0 < KNN) ? n0 : inf2;
      h1 = (c1 < KNN) ? n1 : inf2;
      h2 = (c2 < KNN) ? n2 : inf2;
      h3 = (c3 < KNN) ? n3 : inf2;
    }
  }

  // ---- R30 tail: fused A/Q pass (former aq_kernel; A-frags still live) ----
  {
    unsigned short* Ab = Ab16 + (size_t)b * NN * OO;
    float* Qb = Q + (size_t)b * NN * OO;
#pragma unroll 2
    for (int ot = 0; ot < 8; ++ot) {
      const unsigned short* wrow = Wsp + (size_t)(ot * 16 + c) * WSPL + q * 8;
      const bf16x8 Ph0 = *(const bf16x8*)(wrow);
      const bf16x8 Ph1 = *(const bf16x8*)(wrow + 32);
      const bf16x8 Pm0 = *(const bf16x8*)(wrow + 128);
      const bf16x8 Pm1 = *(const bf16x8*)(wrow + 160);
      const bf16x8 Pl0 = *(const bf16x8*)(wrow + 256);
      const bf16x8 Pl1 = *(const bf16x8*)(wrow + 288);
      MFMA6(accP, Ph0, Ph1, Pm0, Pm1, Pl0, Pl1)
      const bf16x8 Gh0 = *(const bf16x8*)(wrow + 64);
      const bf16x8 Gh1 = *(const bf16x8*)(wrow + 96);
      const bf16x8 Gm0 = *(const bf16x8*)(wrow + 192);
      const bf16x8 Gm1 = *(const bf16x8*)(wrow + 224);
      const bf16x8 Gl0 = *(const bf16x8*)(wrow + 320);
      const bf16x8 Gl1 = *(const bf16x8*)(wrow + 352);
      MFMA6(accG, Gh0, Gh1, Gm0, Gm1, Gl0, Gl1)

      const float bv = bias[ot * 16 + c];
#pragma unroll
      for (int i = 0; i < 4; ++i) {
        const size_t row = (size_t)(ibase + q * 4 + i);
        const float p = accP[i];
        Ab[row * OO + ot * 16 + c] = (unsigned short)rne_bf16(p);
        Qb[row * OO + ot * 16 + c] = accG[i] - p + bv;
      }
    }
  }
}

// ---------------------------------------------------------------------------
// Kernel 4: gather + max + leaky + transposed store (R30 version).
// ---------------------------------------------------------------------------
__global__ __launch_bounds__(256) void gather_kernel(
    const unsigned short* __restrict__ Ab16, const float* __restrict__ Q,
    const int* __restrict__ idxf, float* __restrict__ out) {
  __shared__ int jidx[KNN][32];
  __shared__ float ob[32][OO + 1];

  const int b = blockIdx.y;
  const int n0 = blockIdx.x * 32;
  const int t = threadIdx.x;
  const int p = t & 31;   // channel quad: cols 4p..4p+3
  const int h = t >> 5;   // ii quad: rows h*4..h*4+3

  for (int e = t; e < KNN * 32; e += 256) {
    const int k = e >> 5, ii = e & 31;
    jidx[k][ii] = idxf[((size_t)b * KNN + k) * NN + n0 + ii];
  }
  __syncthreads();

  const unsigned short* Ab = Ab16 + (size_t)b * NN * OO;
  const float* Qb = Q + (size_t)b * NN * OO;

  for (int ii = h * 4; ii < h * 4 + 4; ++ii) {
    float m0 = -1e30f, m1 = -1e30f, m2 = -1e30f, m3 = -1e30f;
#pragma unroll
    for (int k = 0; k < KNN; ++k) {
      const uint2 v =
          *(const uint2*)(Ab + (size_t)jidx[k][ii] * OO + 4 * p);
      m0 = fmaxf(m0, __uint_as_float(v.x << 16));
      m1 = fmaxf(m1, __uint_as_float(v.x & 0xFFFF0000u));
      m2 = fmaxf(m2, __uint_as_float(v.y << 16));
      m3 = fmaxf(m3, __uint_as_float(v.y & 0xFFFF0000u));
    }
    const float4 qv = *(const float4*)(Qb + (size_t)(n0 + ii) * OO + 4 * p);
    const float h0 = m0 + qv.x;
    const float h1 = m1 + qv.y;
    const float h2 = m2 + qv.z;
    const float h3 = m3 + qv.w;
    ob[ii][4 * p + 0] = (h0 >= 0.f) ? h0 : 0.2f * h0;
    ob[ii][4 * p + 1] = (h1 >= 0.f) ? h1 : 0.2f * h1;
    ob[ii][4 * p + 2] = (h2 >= 0.f) ? h2 : 0.2f * h2;
    ob[ii][4 * p + 3] = (h3 >= 0.f) ? h3 : 0.2f * h3;
  }
  __syncthreads();

  float* ou = out + (size_t)b * OO * NN;
  for (int e = t; e < 32 * OO; e += 256) {
    const int ii = e & 31, oo = e >> 5;
    ou[(size_t)oo * NN + n0 + ii] = ob[ii][oo];
  }
}

// ---------------------------------------------------------------------------
extern "C" void kernel_launch(void* const* d_in, const int* in_sizes, int n_in,
                              void* d_out, int out_size, void* d_ws,
                              size_t ws_size, hipStream_t stream) {
  (void)in_sizes;
  (void)n_in;
  (void)out_size;
  (void)ws_size;
  const float* x = (const float*)d_in[0];
  const float* W = (const float*)d_in[1];
  const float* bias = (const float*)d_in[2];
  float* out = (float*)d_out;

  char* ws = (char*)d_ws;
  size_t off = 0;
  unsigned short* Ab16 = (unsigned short*)(ws + off);
  off += (size_t)BB * NN * OO * 2;              // 8 MB
  float* Q = (float*)(ws + off);
  off += (size_t)BB * NN * OO * 4;              // 16 MB
  float* xsq = (float*)(ws + off);
  off += (size_t)BB * NN * 4;                   // 128 KB
  unsigned short* xsp = (unsigned short*)(ws + off);
  off += (size_t)BB * NN * SPLITW * 2;          // 12.6 MB
  int* idxf = (int*)(ws + off);
  off += (size_t)BB * KNN * NN * 4;             // 2.6 MB
  unsigned short* Wsp = (unsigned short*)(ws + off);
  off += (size_t)OO * WSPL * 2;                 // 96 KB

  xprep_kernel<<<dim3(NN / 128, BB), 128, 0, stream>>>(x, W, xsq, xsp, Wsp);
  knn_kernel<<<dim3(NN / 64, BB), 256, 0, stream>>>(xsp, xsq, Wsp, bias,
                                                    Ab16, Q, idxf);
  gather_kernel<<<dim3(NN / 32, BB), 256, 0, stream>>>(Ab16, Q, idxf, out);
}

// Round 14
// 446.063 us; speedup vs baseline: 1.0367x; 1.0367x over previous
//
#include <hip/hip_runtime.h>

#define BB 8
#define CC 64
#define OO 128
#define NN 4096
#define KNN 20
#define NT 256          // 16-j tiles per batch scan
#define NG 64           // 4-tile groups
#define RING 9          // per-lane LDS ring slots
#define TRIG 5          // drain when any lane cnt>=5 (growth <=4/tile -> <=8)
#define SPLITW 192      // xsp row: 64 bf16 h | 64 bf16 m | 64 bf16 l (384 B)
#define WSPL 384        // Wsp row: 128 bf16 h | 128 m | 128 l (768 B)
#define TILEB (16 * SPLITW * 2)  // 6144 B per 16-row B tile

typedef short bf16x8 __attribute__((ext_vector_type(8)));
typedef float f32x4 __attribute__((ext_vector_type(4)));
typedef const __attribute__((address_space(1))) unsigned int* gas_ptr;
typedef __attribute__((address_space(3))) unsigned int* las_ptr;

// ===========================================================================
// knn ledger: R17 barrier-lockstep main loop = ~349us (VERBATIM; 5 structural
// attacks regressed; 2-blocks/CU pinned by grid x LDS-granularity).
// R22 precompute split / R23 MFMA precompute / R26-R27 fused branch-free
// merge tail / R30 fused A/Q pass: total 688 -> 447.8us.
// R31 (FAIL +15us): wsplit folded into xprep block(0,0) -- SERIAL 128-row
//   loop made that block the xprep straggler, delaying knn start.
// R32: keep fold, parallelize: block (bx,0) splits W rows 4bx..4bx+3
//   (uniform ~<1us extra per block, no straggler).
// ===========================================================================
#define REP20(F, P) F(P,0) F(P,1) F(P,2) F(P,3) F(P,4) F(P,5) F(P,6) F(P,7) \
    F(P,8) F(P,9) F(P,10) F(P,11) F(P,12) F(P,13) F(P,14) F(P,15) F(P,16)   \
    F(P,17) F(P,18) F(P,19)

#define TS_DECL(P,k) float P##m##k = 1e30f; int P##p##k = -1;
#define TS_REPL(P,k)                                                        \
  { const bool _h = (P##kpos == (k));                                       \
    P##m##k = _h ? _d : P##m##k;                                            \
    P##p##k = _h ? _j : P##p##k; }

#define TS_N(vd, xd, va, xa, vb, xb)                                        \
  { const bool _g = (vb) > (va); vd = _g ? (vb) : (va); xd = _g ? (xb) : (xa); }

#define TS_TREE(P)                                                          \
  { float t0,t1,t2,t3,t4,t5,t6,t7,t8,t9; int y0,y1,y2,y3,y4,y5,y6,y7,y8,y9; \
    TS_N(t0,y0, P##m0,0,  P##m1,1)   TS_N(t1,y1, P##m2,2,  P##m3,3)         \
    TS_N(t2,y2, P##m4,4,  P##m5,5)   TS_N(t3,y3, P##m6,6,  P##m7,7)         \
    TS_N(t4,y4, P##m8,8,  P##m9,9)   TS_N(t5,y5, P##m10,10, P##m11,11)      \
    TS_N(t6,y6, P##m12,12, P##m13,13) TS_N(t7,y7, P##m14,14, P##m15,15)     \
    TS_N(t8,y8, P##m16,16, P##m17,17) TS_N(t9,y9, P##m18,18, P##m19,19)     \
    float u0,u1,u2,u3,u4; int z0,z1,z2,z3,z4;                               \
    TS_N(u0,z0, t0,y0, t1,y1) TS_N(u1,z1, t2,y2, t3,y3)                     \
    TS_N(u2,z2, t4,y4, t5,y5) TS_N(u3,z3, t6,y6, t7,y7)                     \
    TS_N(u4,z4, t8,y8, t9,y9)                                               \
    float w0,w1; int q0,q1;                                                 \
    TS_N(w0,q0, u0,z0, u1,z1) TS_N(w1,q1, u2,z2, u3,z3)                     \
    float e0; int r0;                                                       \
    TS_N(e0,r0, w0,q0, w1,q1)                                               \
    TS_N(P##kmax, P##kpos, e0,r0, u4,z4) }

#define TS_INS(P, dval, jval)                                               \
  { const float _d = (dval); const int _j = (jval);                         \
    REP20(TS_REPL, P)                                                       \
    TS_TREE(P) }

// row-threshold refresh: rt = min(kmax over the 4 lanes sharing myrow)
#define RT_UPDATE                                                           \
  { const int _s1 = __builtin_amdgcn_ds_swizzle(__float_as_int(A_kmax), 0x101F); \
    const float _m1 = fminf(A_kmax, __int_as_float(_s1));                   \
    const int _s2 = __builtin_amdgcn_ds_swizzle(__float_as_int(_m1), 0x201F); \
    rt = fminf(_m1, __int_as_float(_s2)); }

// ---- branch-free lex compare-swap on A_ slots (ascending) ----
#define MSW(a, b)                                                           \
  { const bool _s = (A_m##b < A_m##a) ||                                    \
                    ((A_m##b == A_m##a) && (A_p##b < A_p##a));              \
    const float _fa = _s ? A_m##b : A_m##a;                                 \
    const float _fb = _s ? A_m##a : A_m##b;                                 \
    const int _ia = _s ? A_p##b : A_p##a;                                   \
    const int _ib = _s ? A_p##a : A_p##b;                                   \
    A_m##a = _fa; A_m##b = _fb; A_p##a = _ia; A_p##b = _ib; }

#define SRND_E MSW(0,1) MSW(2,3) MSW(4,5) MSW(6,7) MSW(8,9) MSW(10,11)      \
    MSW(12,13) MSW(14,15) MSW(16,17) MSW(18,19)
#define SRND_O MSW(1,2) MSW(3,4) MSW(5,6) MSW(7,8) MSW(9,10) MSW(11,12)     \
    MSW(13,14) MSW(15,16) MSW(17,18)
// odd-even transposition sort: 20 rounds suffice for 20 elements
#define SORT20 SRND_E SRND_O SRND_E SRND_O SRND_E SRND_O SRND_E SRND_O      \
    SRND_E SRND_O SRND_E SRND_O SRND_E SRND_O SRND_E SRND_O SRND_E SRND_O  \
    SRND_E SRND_O

__device__ __forceinline__ unsigned rne_bf16(float f) {
  const unsigned u = __float_as_uint(f);
  return (u + 0x7fffu + ((u >> 16) & 1u)) >> 16;
}

// ---------------------------------------------------------------------------
// Kernel 1: per-point xsq + 3-split xsp; blocks (bx,0) also split W rows
// 4bx..4bx+3 -> Wsp (R32: parallelized fold, no straggler).
// ---------------------------------------------------------------------------
__global__ __launch_bounds__(128, 3) void xprep_kernel(
    const float* __restrict__ x, const float* __restrict__ W,
    float* __restrict__ xsq, unsigned short* __restrict__ xsp,
    unsigned short* __restrict__ Wsp) {
  const int b = blockIdx.y;
  const int n = blockIdx.x * 128 + threadIdx.x;

  if (b == 0) {
    const int t = threadIdx.x;  // column
    const int o0 = blockIdx.x * 4;
#pragma unroll
    for (int oo = 0; oo < 4; ++oo) {
      const int o = o0 + oo;
      const float w = W[(size_t)o * (2 * CC) + t];
      const unsigned h = rne_bf16(w);
      const float r = w - __uint_as_float(h << 16);
      const unsigned m = rne_bf16(r);
      const float s = r - __uint_as_float(m << 16);
      const unsigned l = rne_bf16(s);
      unsigned short* row = Wsp + (size_t)o * WSPL;
      row[t] = (unsigned short)h;
      row[128 + t] = (unsigned short)m;
      row[256 + t] = (unsigned short)l;
    }
  }

  const float* xb = x + (size_t)b * CC * NN;

  float xr[CC];
  float sq = 0.f;
#pragma unroll
  for (int c = 0; c < CC; ++c) {
    xr[c] = xb[(size_t)c * NN + n];
    sq = fmaf(xr[c], xr[c], sq);
  }
  xsq[(size_t)b * NN + n] = sq;

  unsigned* srow = (unsigned*)(xsp + ((size_t)b * NN + n) * SPLITW);
#pragma unroll
  for (int c = 0; c < CC; c += 2) {
    const unsigned h0 = rne_bf16(xr[c]), h1 = rne_bf16(xr[c + 1]);
    const float r0 = xr[c] - __uint_as_float(h0 << 16);
    const float r1 = xr[c + 1] - __uint_as_float(h1 << 16);
    const unsigned m0 = rne_bf16(r0), m1 = rne_bf16(r1);
    const float s0 = r0 - __uint_as_float(m0 << 16);
    const float s1 = r1 - __uint_as_float(m1 << 16);
    const unsigned l0 = rne_bf16(s0), l1 = rne_bf16(s1);
    srow[c / 2] = h0 | (h1 << 16);
    srow[32 + c / 2] = m0 | (m1 << 16);
    srow[64 + c / 2] = l0 | (l1 << 16);
  }
}

// ---------------------------------------------------------------------------
// 3-split 6-product MFMA (proven pattern; used by knn tiles and fused A/Q).
// ---------------------------------------------------------------------------
#define MFMA6(ACC, B0, B1, B2, B3, B4, B5)                                  \
  f32x4 ACC;                                                                \
  { f32x4 a0 = {0.f,0.f,0.f,0.f}; f32x4 a1 = {0.f,0.f,0.f,0.f};             \
    f32x4 a2 = {0.f,0.f,0.f,0.f}; f32x4 a3 = {0.f,0.f,0.f,0.f};             \
    a0 = __builtin_amdgcn_mfma_f32_16x16x32_bf16(Ah0, B0, a0, 0, 0, 0);     \
    a1 = __builtin_amdgcn_mfma_f32_16x16x32_bf16(Ah1, B1, a1, 0, 0, 0);     \
    a2 = __builtin_amdgcn_mfma_f32_16x16x32_bf16(Ah0, B2, a2, 0, 0, 0);     \
    a3 = __builtin_amdgcn_mfma_f32_16x16x32_bf16(Ah1, B3, a3, 0, 0, 0);     \
    a0 = __builtin_amdgcn_mfma_f32_16x16x32_bf16(Am0, B0, a0, 0, 0, 0);     \
    a1 = __builtin_amdgcn_mfma_f32_16x16x32_bf16(Am1, B1, a1, 0, 0, 0);     \
    a2 = __builtin_amdgcn_mfma_f32_16x16x32_bf16(Ah0, B4, a2, 0, 0, 0);     \
    a3 = __builtin_amdgcn_mfma_f32_16x16x32_bf16(Ah1, B5, a3, 0, 0, 0);     \
    a0 = __builtin_amdgcn_mfma_f32_16x16x32_bf16(Al0, B0, a0, 0, 0, 0);     \
    a1 = __builtin_amdgcn_mfma_f32_16x16x32_bf16(Al1, B1, a1, 0, 0, 0);     \
    a2 = __builtin_amdgcn_mfma_f32_16x16x32_bf16(Am0, B2, a2, 0, 0, 0);     \
    a3 = __builtin_amdgcn_mfma_f32_16x16x32_bf16(Am1, B3, a3, 0, 0, 0);     \
    ACC = (a0 + a1) + (a2 + a3); }

// ---------------------------------------------------------------------------
// Kernel 2: MFMA Gram-matrix kNN (main loop = R17 VERBATIM).
// Tail: sort+4-way merge (R27) then fused A/Q pass (R30).
// ---------------------------------------------------------------------------
#define STAGEG(G, BUF)                                                      \
  { const char* tb = (const char*)xspB + (size_t)(4 * (G) + wv) * TILEB + gof; \
    char* lb = (char*)(BUF) + wv * 6144;                                    \
    __builtin_amdgcn_global_load_lds((gas_ptr)(const void*)(tb), (las_ptr)(void*)(lb), 16, 0, 0); \
    __builtin_amdgcn_global_load_lds((gas_ptr)(const void*)(tb + 64), (las_ptr)(void*)(lb + 1024), 16, 0, 0); \
    __builtin_amdgcn_global_load_lds((gas_ptr)(const void*)(tb + 128), (las_ptr)(void*)(lb + 2048), 16, 0, 0); \
    __builtin_amdgcn_global_load_lds((gas_ptr)(const void*)(tb + 192), (las_ptr)(void*)(lb + 3072), 16, 0, 0); \
    __builtin_amdgcn_global_load_lds((gas_ptr)(const void*)(tb + 256), (las_ptr)(void*)(lb + 4096), 16, 0, 0); \
    __builtin_amdgcn_global_load_lds((gas_ptr)(const void*)(tb + 320), (las_ptr)(void*)(lb + 5120), 16, 0, 0); }

#define TILE_MFMA_L(LBUF, BUF)                                              \
  { const char* bb = (const char*)(LBUF) + c16;                             \
    const bf16x8 Bh0 = *(const bf16x8*)(bb + (q + 0) * 256);                \
    const bf16x8 Bh1 = *(const bf16x8*)(bb + (q + 4) * 256);                \
    const bf16x8 Bm0 = *(const bf16x8*)(bb + (q + 8) * 256);                \
    const bf16x8 Bm1 = *(const bf16x8*)(bb + (q + 12) * 256);               \
    const bf16x8 Bl0 = *(const bf16x8*)(bb + (q + 16) * 256);               \
    const bf16x8 Bl1 = *(const bf16x8*)(bb + (q + 20) * 256);               \
    f32x4 ac0 = {0.f, 0.f, 0.f, 0.f};                                       \
    f32x4 ac1 = {0.f, 0.f, 0.f, 0.f};                                       \
    f32x4 ac2 = {0.f, 0.f, 0.f, 0.f};                                       \
    f32x4 ac3 = {0.f, 0.f, 0.f, 0.f};                                       \
    ac0 = __builtin_amdgcn_mfma_f32_16x16x32_bf16(Ah0, Bh0, ac0, 0, 0, 0);  \
    ac1 = __builtin_amdgcn_mfma_f32_16x16x32_bf16(Ah1, Bh1, ac1, 0, 0, 0);  \
    ac2 = __builtin_amdgcn_mfma_f32_16x16x32_bf16(Ah0, Bm0, ac2, 0, 0, 0);  \
    ac3 = __builtin_amdgcn_mfma_f32_16x16x32_bf16(Ah1, Bm1, ac3, 0, 0, 0);  \
    ac0 = __builtin_amdgcn_mfma_f32_16x16x32_bf16(Am0, Bh0, ac0, 0, 0, 0);  \
    ac1 = __builtin_amdgcn_mfma_f32_16x16x32_bf16(Am1, Bh1, ac1, 0, 0, 0);  \
    ac2 = __builtin_amdgcn_mfma_f32_16x16x32_bf16(Ah0, Bl0, ac2, 0, 0, 0);  \
    ac3 = __builtin_amdgcn_mfma_f32_16x16x32_bf16(Ah1, Bl1, ac3, 0, 0, 0);  \
    ac0 = __builtin_amdgcn_mfma_f32_16x16x32_bf16(Al0, Bh0, ac0, 0, 0, 0);  \
    ac1 = __builtin_amdgcn_mfma_f32_16x16x32_bf16(Al1, Bh1, ac1, 0, 0, 0);  \
    ac2 = __builtin_amdgcn_mfma_f32_16x16x32_bf16(Am0, Bm0, ac2, 0, 0, 0);  \
    ac3 = __builtin_amdgcn_mfma_f32_16x16x32_bf16(Am1, Bm1, ac3, 0, 0, 0);  \
    const f32x4 acc = (ac0 + ac1) + (ac2 + ac3);                            \
    float* bw = &bounce[BUF][wv][0];                                        \
    bw[(q * 4 + 0) * 20 + c] = acc[0];                                      \
    bw[(q * 4 + 1) * 20 + c] = acc[1];                                      \
    bw[(q * 4 + 2) * 20 + c] = acc[2];                                      \
    bw[(q * 4 + 3) * 20 + c] = acc[3]; }

#define TILE_VALS(T, BUF)                                                   \
  const float* br = &bounce[BUF][wv][myrow * 20 + 4 * g];                   \
  const f32x4 dots = *(const f32x4*)br;                                     \
  const float4 xx = *(const float4*)(xsqb + (T) * 16 + 4 * g);              \
  const float d0 = fmaf(-2.f, dots[0], xx.x);                               \
  const float d1 = fmaf(-2.f, dots[1], xx.y);                               \
  const float d2 = fmaf(-2.f, dots[2], xx.z);                               \
  const float d3 = fmaf(-2.f, dots[3], xx.w);                               \
  const int jb = (T) * 16 + 4 * g;

#define TILE_SELF(T, BUF, K0, K1, K2, K3)                                   \
  { TILE_VALS(T, BUF)                                                       \
    A_m##K0 = d0; A_p##K0 = jb;                                             \
    A_m##K1 = d1; A_p##K1 = jb + 1;                                         \
    A_m##K2 = d2; A_p##K2 = jb + 2;                                         \
    A_m##K3 = d3; A_p##K3 = jb + 3; }

#define TILE_SEL(T, BUF)                                                    \
  { TILE_VALS(T, BUF)                                                       \
    if (d0 <= rt) { myring[cnt] = make_float2(d0, __int_as_float(jb)); ++cnt; } \
    if (d1 <= rt) { myring[cnt] = make_float2(d1, __int_as_float(jb + 1)); ++cnt; } \
    if (d2 <= rt) { myring[cnt] = make_float2(d2, __int_as_float(jb + 2)); ++cnt; } \
    if (d3 <= rt) { myring[cnt] = make_float2(d3, __int_as_float(jb + 3)); ++cnt; } \
    if (__ballot(cnt >= TRIG)) {                                            \
      for (int _k = 0; _k < cnt; ++_k) {                                    \
        const float2 e = myring[_k];                                        \
        if (e.x < A_kmax) { TS_INS(A_, e.x, __float_as_int(e.y)) }          \
      }                                                                     \
      cnt = 0;                                                              \
    }                                                                       \
    RT_UPDATE }

__global__ __launch_bounds__(256, 2) void knn_kernel(
    const unsigned short* __restrict__ xsp, const float* __restrict__ xsq,
    const unsigned short* __restrict__ Wsp, const float* __restrict__ bias,
    unsigned short* __restrict__ Ab16, float* __restrict__ Q,
    int* __restrict__ idxf) {
  __shared__ unsigned short Bbuf0[4 * TILEB / 2];  // 24 KB (even groups)
  __shared__ unsigned short Bbuf1[4 * TILEB / 2];  // 24 KB (odd groups)
  __shared__ float bounce[2][4][16 * 20];          // 10 KB
  __shared__ float2 ring[256][RING];               // 18 KB

  const int b = blockIdx.y;
  const int wv = threadIdx.x >> 6;
  const int lane = threadIdx.x & 63;
  const int q = lane >> 4;
  const int c = lane & 15;
  const int c16 = c * 16;
  const int gof = c * 384 + q * 16;  // staging source offset (k adds 64)
  const int ibase = blockIdx.x * 64 + wv * 16;
  const int myrow = q * 4 + (c & 3);
  const int g = c >> 2;
  const int isel = ibase + myrow;

  const unsigned short* xspB = xsp + (size_t)b * NN * SPLITW;
  const float* xsqb = xsq + (size_t)b * NN;

  // A fragments: rows ibase+c, k-slice quad*8 (+32 for k-chunk 1)
  const unsigned short* arow = xspB + (size_t)(ibase + c) * SPLITW + q * 8;
  const bf16x8 Ah0 = *(const bf16x8*)(arow);
  const bf16x8 Ah1 = *(const bf16x8*)(arow + 32);
  const bf16x8 Am0 = *(const bf16x8*)(arow + 64);
  const bf16x8 Am1 = *(const bf16x8*)(arow + 96);
  const bf16x8 Al0 = *(const bf16x8*)(arow + 128);
  const bf16x8 Al1 = *(const bf16x8*)(arow + 160);

  REP20(TS_DECL, A_)
  float A_kmax = 1e30f; int A_kpos = 0;
  float rt = 1e30f;
  float2* myring = ring[threadIdx.x];
  int cnt = 0;

  // ---- prologue ----
  STAGEG(0, Bbuf0)
  __syncthreads();
  STAGEG(1, Bbuf1)
  TILE_MFMA_L(Bbuf0 + 0 * 3072, 0)
  TILE_MFMA_L(Bbuf0 + 1 * 3072, 1) TILE_SELF(0, 0, 0, 1, 2, 3)
  TILE_MFMA_L(Bbuf0 + 2 * 3072, 0) TILE_SELF(1, 1, 4, 5, 6, 7)
  TILE_MFMA_L(Bbuf0 + 3 * 3072, 1) TILE_SELF(2, 0, 8, 9, 10, 11)
  __syncthreads();
  STAGEG(2, Bbuf0)
  TILE_MFMA_L(Bbuf1 + 0 * 3072, 0) TILE_SELF(3, 1, 12, 13, 14, 15)
  TILE_MFMA_L(Bbuf1 + 1 * 3072, 1) TILE_SELF(4, 0, 16, 17, 18, 19)
  TS_TREE(A_)
  RT_UPDATE
  TILE_MFMA_L(Bbuf1 + 2 * 3072, 0) TILE_SEL(5, 1)
  TILE_MFMA_L(Bbuf1 + 3 * 3072, 1) TILE_SEL(6, 0)
  __syncthreads();

  // ---- steady state: groups 2..62 ----
  for (int G = 2; G < NG - 1; ++G) {
    unsigned short* cur = (G & 1) ? Bbuf1 : Bbuf0;
    unsigned short* nxt = (G & 1) ? Bbuf0 : Bbuf1;
    STAGEG(G + 1, nxt)
    const int t0 = 4 * G;
    TILE_MFMA_L(cur + 0 * 3072, 0) TILE_SEL(t0 - 1, 1)
    TILE_MFMA_L(cur + 1 * 3072, 1) TILE_SEL(t0, 0)
    TILE_MFMA_L(cur + 2 * 3072, 0) TILE_SEL(t0 + 1, 1)
    TILE_MFMA_L(cur + 3 * 3072, 1) TILE_SEL(t0 + 2, 0)
    __syncthreads();
  }

  // ---- epilogue: group 63 (tiles 252..255 in Bbuf1), no staging ----
  TILE_MFMA_L(Bbuf1 + 0 * 3072, 0) TILE_SEL(251, 1)
  TILE_MFMA_L(Bbuf1 + 1 * 3072, 1) TILE_SEL(252, 0)
  TILE_MFMA_L(Bbuf1 + 2 * 3072, 0) TILE_SEL(253, 1)
  TILE_MFMA_L(Bbuf1 + 3 * 3072, 1) TILE_SEL(254, 0)
  TILE_SEL(255, 1)

  // final drain
  for (int _k = 0; _k < cnt; ++_k) {
    const float2 e = myring[_k];
    if (e.x < A_kmax) { TS_INS(A_, e.x, __float_as_int(e.y)) }
  }

  // ---- R27 tail: branch-free sort + 4-way sorted merge ----
  __syncthreads();
  {
    SORT20
    float2* dumpw = (float2*)((wv & 2) ? (char*)Bbuf1 + (wv & 1) * 10752
                                       : (char*)Bbuf0 + (wv & 1) * 10752);
    float2* mydump = dumpw + lane * 21;
#define MG_DUMP(P, k) mydump[k] = make_float2(P##m##k, __int_as_float(P##p##k));
    REP20(MG_DUMP, A_)
#undef MG_DUMP
    const int srow = q * 16 + (c & 3);
    const float2* l0 = dumpw + (size_t)(srow + 0) * 21;
    const float2* l1 = dumpw + (size_t)(srow + 4) * 21;
    const float2* l2 = dumpw + (size_t)(srow + 8) * 21;
    const float2* l3 = dumpw + (size_t)(srow + 12) * 21;
    int c0 = 0, c1 = 0, c2 = 0, c3 = 0;
    float2 h0 = l0[0], h1 = l1[0], h2 = l2[0], h3 = l3[0];
    const size_t obase = (size_t)b * KNN * NN + isel;
    for (int k = 0; k < KNN; ++k) {
      const bool s01 =
          (h1.x < h0.x) ||
          ((h1.x == h0.x) && (__float_as_int(h1.y) < __float_as_int(h0.y)));
      const float2 m01 = s01 ? h1 : h0;
      const bool s23 =
          (h3.x < h2.x) ||
          ((h3.x == h2.x) && (__float_as_int(h3.y) < __float_as_int(h2.y)));
      const float2 m23 = s23 ? h3 : h2;
      const bool sF =
          (m23.x < m01.x) ||
          ((m23.x == m01.x) && (__float_as_int(m23.y) < __float_as_int(m01.y)));
      const float2 mm = sF ? m23 : m01;
      if (g == 0) idxf[obase + (size_t)k * NN] = __float_as_int(mm.y);
      const int w = sF ? (s23 ? 3 : 2) : (s01 ? 1 : 0);
      c0 += (w == 0); c1 += (w == 1); c2 += (w == 2); c3 += (w == 3);
      const float2 n0 = l0[c0], n1 = l1[c1], n2 = l2[c2], n3 = l3[c3];
      const float2 inf2 = make_float2(1e30f, __int_as_float(0x7fffffff));
      h0 = (c0 < KNN) ? n0 : inf2;
      h1 = (c1 < KNN) ? n1 : inf2;
      h2 = (c2 < KNN) ? n2 : inf2;
      h3 = (c3 < KNN) ? n3 : inf2;
    }
  }

  // ---- R30 tail: fused A/Q pass (former aq_kernel; A-frags still live) ----
  {
    unsigned short* Ab = Ab16 + (size_t)b * NN * OO;
    float* Qb = Q + (size_t)b * NN * OO;
#pragma unroll 2
    for (int ot = 0; ot < 8; ++ot) {
      const unsigned short* wrow = Wsp + (size_t)(ot * 16 + c) * WSPL + q * 8;
      const bf16x8 Ph0 = *(const bf16x8*)(wrow);
      const bf16x8 Ph1 = *(const bf16x8*)(wrow + 32);
      const bf16x8 Pm0 = *(const bf16x8*)(wrow + 128);
      const bf16x8 Pm1 = *(const bf16x8*)(wrow + 160);
      const bf16x8 Pl0 = *(const bf16x8*)(wrow + 256);
      const bf16x8 Pl1 = *(const bf16x8*)(wrow + 288);
      MFMA6(accP, Ph0, Ph1, Pm0, Pm1, Pl0, Pl1)
      const bf16x8 Gh0 = *(const bf16x8*)(wrow + 64);
      const bf16x8 Gh1 = *(const bf16x8*)(wrow + 96);
      const bf16x8 Gm0 = *(const bf16x8*)(wrow + 192);
      const bf16x8 Gm1 = *(const bf16x8*)(wrow + 224);
      const bf16x8 Gl0 = *(const bf16x8*)(wrow + 320);
      const bf16x8 Gl1 = *(const bf16x8*)(wrow + 352);
      MFMA6(accG, Gh0, Gh1, Gm0, Gm1, Gl0, Gl1)

      const float bv = bias[ot * 16 + c];
#pragma unroll
      for (int i = 0; i < 4; ++i) {
        const size_t row = (size_t)(ibase + q * 4 + i);
        const float p = accP[i];
        Ab[row * OO + ot * 16 + c] = (unsigned short)rne_bf16(p);
        Qb[row * OO + ot * 16 + c] = accG[i] - p + bv;
      }
    }
  }
}

// ---------------------------------------------------------------------------
// Kernel 4: gather + max + leaky + transposed store (R30 version).
// ---------------------------------------------------------------------------
__global__ __launch_bounds__(256) void gather_kernel(
    const unsigned short* __restrict__ Ab16, const float* __restrict__ Q,
    const int* __restrict__ idxf, float* __restrict__ out) {
  __shared__ int jidx[KNN][32];
  __shared__ float ob[32][OO + 1];

  const int b = blockIdx.y;
  const int n0 = blockIdx.x * 32;
  const int t = threadIdx.x;
  const int p = t & 31;   // channel quad: cols 4p..4p+3
  const int h = t >> 5;   // ii quad: rows h*4..h*4+3

  for (int e = t; e < KNN * 32; e += 256) {
    const int k = e >> 5, ii = e & 31;
    jidx[k][ii] = idxf[((size_t)b * KNN + k) * NN + n0 + ii];
  }
  __syncthreads();

  const unsigned short* Ab = Ab16 + (size_t)b * NN * OO;
  const float* Qb = Q + (size_t)b * NN * OO;

  for (int ii = h * 4; ii < h * 4 + 4; ++ii) {
    float m0 = -1e30f, m1 = -1e30f, m2 = -1e30f, m3 = -1e30f;
#pragma unroll
    for (int k = 0; k < KNN; ++k) {
      const uint2 v =
          *(const uint2*)(Ab + (size_t)jidx[k][ii] * OO + 4 * p);
      m0 = fmaxf(m0, __uint_as_float(v.x << 16));
      m1 = fmaxf(m1, __uint_as_float(v.x & 0xFFFF0000u));
      m2 = fmaxf(m2, __uint_as_float(v.y << 16));
      m3 = fmaxf(m3, __uint_as_float(v.y & 0xFFFF0000u));
    }
    const float4 qv = *(const float4*)(Qb + (size_t)(n0 + ii) * OO + 4 * p);
    const float h0 = m0 + qv.x;
    const float h1 = m1 + qv.y;
    const float h2 = m2 + qv.z;
    const float h3 = m3 + qv.w;
    ob[ii][4 * p + 0] = (h0 >= 0.f) ? h0 : 0.2f * h0;
    ob[ii][4 * p + 1] = (h1 >= 0.f) ? h1 : 0.2f * h1;
    ob[ii][4 * p + 2] = (h2 >= 0.f) ? h2 : 0.2f * h2;
    ob[ii][4 * p + 3] = (h3 >= 0.f) ? h3 : 0.2f * h3;
  }
  __syncthreads();

  float* ou = out + (size_t)b * OO * NN;
  for (int e = t; e < 32 * OO; e += 256) {
    const int ii = e & 31, oo = e >> 5;
    ou[(size_t)oo * NN + n0 + ii] = ob[ii][oo];
  }
}

// ---------------------------------------------------------------------------
extern "C" void kernel_launch(void* const* d_in, const int* in_sizes, int n_in,
                              void* d_out, int out_size, void* d_ws,
                              size_t ws_size, hipStream_t stream) {
  (void)in_sizes;
  (void)n_in;
  (void)out_size;
  (void)ws_size;
  const float* x = (const float*)d_in[0];
  const float* W = (const float*)d_in[1];
  const float* bias = (const float*)d_in[2];
  float* out = (float*)d_out;

  char* ws = (char*)d_ws;
  size_t off = 0;
  unsigned short* Ab16 = (unsigned short*)(ws + off);
  off += (size_t)BB * NN * OO * 2;              // 8 MB
  float* Q = (float*)(ws + off);
  off += (size_t)BB * NN * OO * 4;              // 16 MB
  float* xsq = (float*)(ws + off);
  off += (size_t)BB * NN * 4;                   // 128 KB
  unsigned short* xsp = (unsigned short*)(ws + off);
  off += (size_t)BB * NN * SPLITW * 2;          // 12.6 MB
  int* idxf = (int*)(ws + off);
  off += (size_t)BB * KNN * NN * 4;             // 2.6 MB
  unsigned short* Wsp = (unsigned short*)(ws + off);
  off += (size_t)OO * WSPL * 2;                 // 96 KB

  xprep_kernel<<<dim3(NN / 128, BB), 128, 0, stream>>>(x, W, xsq, xsp, Wsp);
  knn_kernel<<<dim3(NN / 64, BB), 256, 0, stream>>>(xsp, xsq, Wsp, bias,
                                                    Ab16, Q, idxf);
  gather_kernel<<<dim3(NN / 32, BB), 256, 0, stream>>>(Ab16, Q, idxf, out);
}

// Round 15
// 438.834 us; speedup vs baseline: 1.0538x; 1.0165x over previous
//
#include <hip/hip_runtime.h>

#define BB 8
#define CC 64
#define OO 128
#define NN 4096
#define KNN 20
#define NT 256          // 16-j tiles per batch scan
#define NG 64           // 4-tile groups
#define RING 9          // per-lane LDS ring slots
#define TRIG 5          // drain when any lane cnt>=5 (growth <=4/tile -> <=8)
#define SPLITW 192      // xsp row: 64 bf16 h | 64 bf16 m | 64 bf16 l (384 B)
#define WSPL 384        // Wsp row: 128 bf16 h | 128 m | 128 l (768 B)
#define TILEB (16 * SPLITW * 2)  // 6144 B per 16-row B tile

typedef short bf16x8 __attribute__((ext_vector_type(8)));
typedef float f32x4 __attribute__((ext_vector_type(4)));
typedef const __attribute__((address_space(1))) unsigned int* gas_ptr;
typedef __attribute__((address_space(3))) unsigned int* las_ptr;

// ===========================================================================
// knn ledger: R17 barrier-lockstep main loop = ~349us (VERBATIM; structural
// plateau: 63 barriers x ~13K cyc wall, latency-bound at 8 waves/CU;
// occupancy pinned ~22% even when LDS+grid allow 3 blocks/CU (R19) --
// all escape routes falsified R18/R19/R20/R21).
// R22/R23/R26/R27/R30/R32: 688 -> 446.1us (MFMA precompute, fused branch-
// free merge tail, fused A/Q, parallelized W-split fold).
// R33: gather latency-hiding -- 512 thr/block, 2 rows/thread (40 scattered
//   uint2 loads vs 80), 8 waves/CU issuing concurrently to hide L2 latency.
// ===========================================================================
#define REP20(F, P) F(P,0) F(P,1) F(P,2) F(P,3) F(P,4) F(P,5) F(P,6) F(P,7) \
    F(P,8) F(P,9) F(P,10) F(P,11) F(P,12) F(P,13) F(P,14) F(P,15) F(P,16)   \
    F(P,17) F(P,18) F(P,19)

#define TS_DECL(P,k) float P##m##k = 1e30f; int P##p##k = -1;
#define TS_REPL(P,k)                                                        \
  { const bool _h = (P##kpos == (k));                                       \
    P##m##k = _h ? _d : P##m##k;                                            \
    P##p##k = _h ? _j : P##p##k; }

#define TS_N(vd, xd, va, xa, vb, xb)                                        \
  { const bool _g = (vb) > (va); vd = _g ? (vb) : (va); xd = _g ? (xb) : (xa); }

#define TS_TREE(P)                                                          \
  { float t0,t1,t2,t3,t4,t5,t6,t7,t8,t9; int y0,y1,y2,y3,y4,y5,y6,y7,y8,y9; \
    TS_N(t0,y0, P##m0,0,  P##m1,1)   TS_N(t1,y1, P##m2,2,  P##m3,3)         \
    TS_N(t2,y2, P##m4,4,  P##m5,5)   TS_N(t3,y3, P##m6,6,  P##m7,7)         \
    TS_N(t4,y4, P##m8,8,  P##m9,9)   TS_N(t5,y5, P##m10,10, P##m11,11)      \
    TS_N(t6,y6, P##m12,12, P##m13,13) TS_N(t7,y7, P##m14,14, P##m15,15)     \
    TS_N(t8,y8, P##m16,16, P##m17,17) TS_N(t9,y9, P##m18,18, P##m19,19)     \
    float u0,u1,u2,u3,u4; int z0,z1,z2,z3,z4;                               \
    TS_N(u0,z0, t0,y0, t1,y1) TS_N(u1,z1, t2,y2, t3,y3)                     \
    TS_N(u2,z2, t4,y4, t5,y5) TS_N(u3,z3, t6,y6, t7,y7)                     \
    TS_N(u4,z4, t8,y8, t9,y9)                                               \
    float w0,w1; int q0,q1;                                                 \
    TS_N(w0,q0, u0,z0, u1,z1) TS_N(w1,q1, u2,z2, u3,z3)                     \
    float e0; int r0;                                                       \
    TS_N(e0,r0, w0,q0, w1,q1)                                               \
    TS_N(P##kmax, P##kpos, e0,r0, u4,z4) }

#define TS_INS(P, dval, jval)                                               \
  { const float _d = (dval); const int _j = (jval);                         \
    REP20(TS_REPL, P)                                                       \
    TS_TREE(P) }

// row-threshold refresh: rt = min(kmax over the 4 lanes sharing myrow)
#define RT_UPDATE                                                           \
  { const int _s1 = __builtin_amdgcn_ds_swizzle(__float_as_int(A_kmax), 0x101F); \
    const float _m1 = fminf(A_kmax, __int_as_float(_s1));                   \
    const int _s2 = __builtin_amdgcn_ds_swizzle(__float_as_int(_m1), 0x201F); \
    rt = fminf(_m1, __int_as_float(_s2)); }

// ---- branch-free lex compare-swap on A_ slots (ascending) ----
#define MSW(a, b)                                                           \
  { const bool _s = (A_m##b < A_m##a) ||                                    \
                    ((A_m##b == A_m##a) && (A_p##b < A_p##a));              \
    const float _fa = _s ? A_m##b : A_m##a;                                 \
    const float _fb = _s ? A_m##a : A_m##b;                                 \
    const int _ia = _s ? A_p##b : A_p##a;                                   \
    const int _ib = _s ? A_p##a : A_p##b;                                   \
    A_m##a = _fa; A_m##b = _fb; A_p##a = _ia; A_p##b = _ib; }

#define SRND_E MSW(0,1) MSW(2,3) MSW(4,5) MSW(6,7) MSW(8,9) MSW(10,11)      \
    MSW(12,13) MSW(14,15) MSW(16,17) MSW(18,19)
#define SRND_O MSW(1,2) MSW(3,4) MSW(5,6) MSW(7,8) MSW(9,10) MSW(11,12)     \
    MSW(13,14) MSW(15,16) MSW(17,18)
// odd-even transposition sort: 20 rounds suffice for 20 elements
#define SORT20 SRND_E SRND_O SRND_E SRND_O SRND_E SRND_O SRND_E SRND_O      \
    SRND_E SRND_O SRND_E SRND_O SRND_E SRND_O SRND_E SRND_O SRND_E SRND_O  \
    SRND_E SRND_O

__device__ __forceinline__ unsigned rne_bf16(float f) {
  const unsigned u = __float_as_uint(f);
  return (u + 0x7fffu + ((u >> 16) & 1u)) >> 16;
}

// ---------------------------------------------------------------------------
// Kernel 1: per-point xsq + 3-split xsp; blocks (bx,0) also split W rows
// 4bx..4bx+3 -> Wsp (parallelized fold, no straggler).
// ---------------------------------------------------------------------------
__global__ __launch_bounds__(128, 3) void xprep_kernel(
    const float* __restrict__ x, const float* __restrict__ W,
    float* __restrict__ xsq, unsigned short* __restrict__ xsp,
    unsigned short* __restrict__ Wsp) {
  const int b = blockIdx.y;
  const int n = blockIdx.x * 128 + threadIdx.x;

  if (b == 0) {
    const int t = threadIdx.x;  // column
    const int o0 = blockIdx.x * 4;
#pragma unroll
    for (int oo = 0; oo < 4; ++oo) {
      const int o = o0 + oo;
      const float w = W[(size_t)o * (2 * CC) + t];
      const unsigned h = rne_bf16(w);
      const float r = w - __uint_as_float(h << 16);
      const unsigned m = rne_bf16(r);
      const float s = r - __uint_as_float(m << 16);
      const unsigned l = rne_bf16(s);
      unsigned short* row = Wsp + (size_t)o * WSPL;
      row[t] = (unsigned short)h;
      row[128 + t] = (unsigned short)m;
      row[256 + t] = (unsigned short)l;
    }
  }

  const float* xb = x + (size_t)b * CC * NN;

  float xr[CC];
  float sq = 0.f;
#pragma unroll
  for (int c = 0; c < CC; ++c) {
    xr[c] = xb[(size_t)c * NN + n];
    sq = fmaf(xr[c], xr[c], sq);
  }
  xsq[(size_t)b * NN + n] = sq;

  unsigned* srow = (unsigned*)(xsp + ((size_t)b * NN + n) * SPLITW);
#pragma unroll
  for (int c = 0; c < CC; c += 2) {
    const unsigned h0 = rne_bf16(xr[c]), h1 = rne_bf16(xr[c + 1]);
    const float r0 = xr[c] - __uint_as_float(h0 << 16);
    const float r1 = xr[c + 1] - __uint_as_float(h1 << 16);
    const unsigned m0 = rne_bf16(r0), m1 = rne_bf16(r1);
    const float s0 = r0 - __uint_as_float(m0 << 16);
    const float s1 = r1 - __uint_as_float(m1 << 16);
    const unsigned l0 = rne_bf16(s0), l1 = rne_bf16(s1);
    srow[c / 2] = h0 | (h1 << 16);
    srow[32 + c / 2] = m0 | (m1 << 16);
    srow[64 + c / 2] = l0 | (l1 << 16);
  }
}

// ---------------------------------------------------------------------------
// 3-split 6-product MFMA (proven pattern; used by knn tiles and fused A/Q).
// ---------------------------------------------------------------------------
#define MFMA6(ACC, B0, B1, B2, B3, B4, B5)                                  \
  f32x4 ACC;                                                                \
  { f32x4 a0 = {0.f,0.f,0.f,0.f}; f32x4 a1 = {0.f,0.f,0.f,0.f};             \
    f32x4 a2 = {0.f,0.f,0.f,0.f}; f32x4 a3 = {0.f,0.f,0.f,0.f};             \
    a0 = __builtin_amdgcn_mfma_f32_16x16x32_bf16(Ah0, B0, a0, 0, 0, 0);     \
    a1 = __builtin_amdgcn_mfma_f32_16x16x32_bf16(Ah1, B1, a1, 0, 0, 0);     \
    a2 = __builtin_amdgcn_mfma_f32_16x16x32_bf16(Ah0, B2, a2, 0, 0, 0);     \
    a3 = __builtin_amdgcn_mfma_f32_16x16x32_bf16(Ah1, B3, a3, 0, 0, 0);     \
    a0 = __builtin_amdgcn_mfma_f32_16x16x32_bf16(Am0, B0, a0, 0, 0, 0);     \
    a1 = __builtin_amdgcn_mfma_f32_16x16x32_bf16(Am1, B1, a1, 0, 0, 0);     \
    a2 = __builtin_amdgcn_mfma_f32_16x16x32_bf16(Ah0, B4, a2, 0, 0, 0);     \
    a3 = __builtin_amdgcn_mfma_f32_16x16x32_bf16(Ah1, B5, a3, 0, 0, 0);     \
    a0 = __builtin_amdgcn_mfma_f32_16x16x32_bf16(Al0, B0, a0, 0, 0, 0);     \
    a1 = __builtin_amdgcn_mfma_f32_16x16x32_bf16(Al1, B1, a1, 0, 0, 0);     \
    a2 = __builtin_amdgcn_mfma_f32_16x16x32_bf16(Am0, B2, a2, 0, 0, 0);     \
    a3 = __builtin_amdgcn_mfma_f32_16x16x32_bf16(Am1, B3, a3, 0, 0, 0);     \
    ACC = (a0 + a1) + (a2 + a3); }

// ---------------------------------------------------------------------------
// Kernel 2: MFMA Gram-matrix kNN (main loop = R17 VERBATIM).
// Tail: sort+4-way merge (R27) then fused A/Q pass (R30).
// ---------------------------------------------------------------------------
#define STAGEG(G, BUF)                                                      \
  { const char* tb = (const char*)xspB + (size_t)(4 * (G) + wv) * TILEB + gof; \
    char* lb = (char*)(BUF) + wv * 6144;                                    \
    __builtin_amdgcn_global_load_lds((gas_ptr)(const void*)(tb), (las_ptr)(void*)(lb), 16, 0, 0); \
    __builtin_amdgcn_global_load_lds((gas_ptr)(const void*)(tb + 64), (las_ptr)(void*)(lb + 1024), 16, 0, 0); \
    __builtin_amdgcn_global_load_lds((gas_ptr)(const void*)(tb + 128), (las_ptr)(void*)(lb + 2048), 16, 0, 0); \
    __builtin_amdgcn_global_load_lds((gas_ptr)(const void*)(tb + 192), (las_ptr)(void*)(lb + 3072), 16, 0, 0); \
    __builtin_amdgcn_global_load_lds((gas_ptr)(const void*)(tb + 256), (las_ptr)(void*)(lb + 4096), 16, 0, 0); \
    __builtin_amdgcn_global_load_lds((gas_ptr)(const void*)(tb + 320), (las_ptr)(void*)(lb + 5120), 16, 0, 0); }

#define TILE_MFMA_L(LBUF, BUF)                                              \
  { const char* bb = (const char*)(LBUF) + c16;                             \
    const bf16x8 Bh0 = *(const bf16x8*)(bb + (q + 0) * 256);                \
    const bf16x8 Bh1 = *(const bf16x8*)(bb + (q + 4) * 256);                \
    const bf16x8 Bm0 = *(const bf16x8*)(bb + (q + 8) * 256);                \
    const bf16x8 Bm1 = *(const bf16x8*)(bb + (q + 12) * 256);               \
    const bf16x8 Bl0 = *(const bf16x8*)(bb + (q + 16) * 256);               \
    const bf16x8 Bl1 = *(const bf16x8*)(bb + (q + 20) * 256);               \
    f32x4 ac0 = {0.f, 0.f, 0.f, 0.f};                                       \
    f32x4 ac1 = {0.f, 0.f, 0.f, 0.f};                                       \
    f32x4 ac2 = {0.f, 0.f, 0.f, 0.f};                                       \
    f32x4 ac3 = {0.f, 0.f, 0.f, 0.f};                                       \
    ac0 = __builtin_amdgcn_mfma_f32_16x16x32_bf16(Ah0, Bh0, ac0, 0, 0, 0);  \
    ac1 = __builtin_amdgcn_mfma_f32_16x16x32_bf16(Ah1, Bh1, ac1, 0, 0, 0);  \
    ac2 = __builtin_amdgcn_mfma_f32_16x16x32_bf16(Ah0, Bm0, ac2, 0, 0, 0);  \
    ac3 = __builtin_amdgcn_mfma_f32_16x16x32_bf16(Ah1, Bm1, ac3, 0, 0, 0);  \
    ac0 = __builtin_amdgcn_mfma_f32_16x16x32_bf16(Am0, Bh0, ac0, 0, 0, 0);  \
    ac1 = __builtin_amdgcn_mfma_f32_16x16x32_bf16(Am1, Bh1, ac1, 0, 0, 0);  \
    ac2 = __builtin_amdgcn_mfma_f32_16x16x32_bf16(Ah0, Bl0, ac2, 0, 0, 0);  \
    ac3 = __builtin_amdgcn_mfma_f32_16x16x32_bf16(Ah1, Bl1, ac3, 0, 0, 0);  \
    ac0 = __builtin_amdgcn_mfma_f32_16x16x32_bf16(Al0, Bh0, ac0, 0, 0, 0);  \
    ac1 = __builtin_amdgcn_mfma_f32_16x16x32_bf16(Al1, Bh1, ac1, 0, 0, 0);  \
    ac2 = __builtin_amdgcn_mfma_f32_16x16x32_bf16(Am0, Bm0, ac2, 0, 0, 0);  \
    ac3 = __builtin_amdgcn_mfma_f32_16x16x32_bf16(Am1, Bm1, ac3, 0, 0, 0);  \
    const f32x4 acc = (ac0 + ac1) + (ac2 + ac3);                            \
    float* bw = &bounce[BUF][wv][0];                                        \
    bw[(q * 4 + 0) * 20 + c] = acc[0];                                      \
    bw[(q * 4 + 1) * 20 + c] = acc[1];                                      \
    bw[(q * 4 + 2) * 20 + c] = acc[2];                                      \
    bw[(q * 4 + 3) * 20 + c] = acc[3]; }

#define TILE_VALS(T, BUF)                                                   \
  const float* br = &bounce[BUF][wv][myrow * 20 + 4 * g];                   \
  const f32x4 dots = *(const f32x4*)br;                                     \
  const float4 xx = *(const float4*)(xsqb + (T) * 16 + 4 * g);              \
  const float d0 = fmaf(-2.f, dots[0], xx.x);                               \
  const float d1 = fmaf(-2.f, dots[1], xx.y);                               \
  const float d2 = fmaf(-2.f, dots[2], xx.z);                               \
  const float d3 = fmaf(-2.f, dots[3], xx.w);                               \
  const int jb = (T) * 16 + 4 * g;

#define TILE_SELF(T, BUF, K0, K1, K2, K3)                                   \
  { TILE_VALS(T, BUF)                                                       \
    A_m##K0 = d0; A_p##K0 = jb;                                             \
    A_m##K1 = d1; A_p##K1 = jb + 1;                                         \
    A_m##K2 = d2; A_p##K2 = jb + 2;                                         \
    A_m##K3 = d3; A_p##K3 = jb + 3; }

#define TILE_SEL(T, BUF)                                                    \
  { TILE_VALS(T, BUF)                                                       \
    if (d0 <= rt) { myring[cnt] = make_float2(d0, __int_as_float(jb)); ++cnt; } \
    if (d1 <= rt) { myring[cnt] = make_float2(d1, __int_as_float(jb + 1)); ++cnt; } \
    if (d2 <= rt) { myring[cnt] = make_float2(d2, __int_as_float(jb + 2)); ++cnt; } \
    if (d3 <= rt) { myring[cnt] = make_float2(d3, __int_as_float(jb + 3)); ++cnt; } \
    if (__ballot(cnt >= TRIG)) {                                            \
      for (int _k = 0; _k < cnt; ++_k) {                                    \
        const float2 e = myring[_k];                                        \
        if (e.x < A_kmax) { TS_INS(A_, e.x, __float_as_int(e.y)) }          \
      }                                                                     \
      cnt = 0;                                                              \
    }                                                                       \
    RT_UPDATE }

__global__ __launch_bounds__(256, 2) void knn_kernel(
    const unsigned short* __restrict__ xsp, const float* __restrict__ xsq,
    const unsigned short* __restrict__ Wsp, const float* __restrict__ bias,
    unsigned short* __restrict__ Ab16, float* __restrict__ Q,
    int* __restrict__ idxf) {
  __shared__ unsigned short Bbuf0[4 * TILEB / 2];  // 24 KB (even groups)
  __shared__ unsigned short Bbuf1[4 * TILEB / 2];  // 24 KB (odd groups)
  __shared__ float bounce[2][4][16 * 20];          // 10 KB
  __shared__ float2 ring[256][RING];               // 18 KB

  const int b = blockIdx.y;
  const int wv = threadIdx.x >> 6;
  const int lane = threadIdx.x & 63;
  const int q = lane >> 4;
  const int c = lane & 15;
  const int c16 = c * 16;
  const int gof = c * 384 + q * 16;  // staging source offset (k adds 64)
  const int ibase = blockIdx.x * 64 + wv * 16;
  const int myrow = q * 4 + (c & 3);
  const int g = c >> 2;
  const int isel = ibase + myrow;

  const unsigned short* xspB = xsp + (size_t)b * NN * SPLITW;
  const float* xsqb = xsq + (size_t)b * NN;

  // A fragments: rows ibase+c, k-slice quad*8 (+32 for k-chunk 1)
  const unsigned short* arow = xspB + (size_t)(ibase + c) * SPLITW + q * 8;
  const bf16x8 Ah0 = *(const bf16x8*)(arow);
  const bf16x8 Ah1 = *(const bf16x8*)(arow + 32);
  const bf16x8 Am0 = *(const bf16x8*)(arow + 64);
  const bf16x8 Am1 = *(const bf16x8*)(arow + 96);
  const bf16x8 Al0 = *(const bf16x8*)(arow + 128);
  const bf16x8 Al1 = *(const bf16x8*)(arow + 160);

  REP20(TS_DECL, A_)
  float A_kmax = 1e30f; int A_kpos = 0;
  float rt = 1e30f;
  float2* myring = ring[threadIdx.x];
  int cnt = 0;

  // ---- prologue ----
  STAGEG(0, Bbuf0)
  __syncthreads();
  STAGEG(1, Bbuf1)
  TILE_MFMA_L(Bbuf0 + 0 * 3072, 0)
  TILE_MFMA_L(Bbuf0 + 1 * 3072, 1) TILE_SELF(0, 0, 0, 1, 2, 3)
  TILE_MFMA_L(Bbuf0 + 2 * 3072, 0) TILE_SELF(1, 1, 4, 5, 6, 7)
  TILE_MFMA_L(Bbuf0 + 3 * 3072, 1) TILE_SELF(2, 0, 8, 9, 10, 11)
  __syncthreads();
  STAGEG(2, Bbuf0)
  TILE_MFMA_L(Bbuf1 + 0 * 3072, 0) TILE_SELF(3, 1, 12, 13, 14, 15)
  TILE_MFMA_L(Bbuf1 + 1 * 3072, 1) TILE_SELF(4, 0, 16, 17, 18, 19)
  TS_TREE(A_)
  RT_UPDATE
  TILE_MFMA_L(Bbuf1 + 2 * 3072, 0) TILE_SEL(5, 1)
  TILE_MFMA_L(Bbuf1 + 3 * 3072, 1) TILE_SEL(6, 0)
  __syncthreads();

  // ---- steady state: groups 2..62 ----
  for (int G = 2; G < NG - 1; ++G) {
    unsigned short* cur = (G & 1) ? Bbuf1 : Bbuf0;
    unsigned short* nxt = (G & 1) ? Bbuf0 : Bbuf1;
    STAGEG(G + 1, nxt)
    const int t0 = 4 * G;
    TILE_MFMA_L(cur + 0 * 3072, 0) TILE_SEL(t0 - 1, 1)
    TILE_MFMA_L(cur + 1 * 3072, 1) TILE_SEL(t0, 0)
    TILE_MFMA_L(cur + 2 * 3072, 0) TILE_SEL(t0 + 1, 1)
    TILE_MFMA_L(cur + 3 * 3072, 1) TILE_SEL(t0 + 2, 0)
    __syncthreads();
  }

  // ---- epilogue: group 63 (tiles 252..255 in Bbuf1), no staging ----
  TILE_MFMA_L(Bbuf1 + 0 * 3072, 0) TILE_SEL(251, 1)
  TILE_MFMA_L(Bbuf1 + 1 * 3072, 1) TILE_SEL(252, 0)
  TILE_MFMA_L(Bbuf1 + 2 * 3072, 0) TILE_SEL(253, 1)
  TILE_MFMA_L(Bbuf1 + 3 * 3072, 1) TILE_SEL(254, 0)
  TILE_SEL(255, 1)

  // final drain
  for (int _k = 0; _k < cnt; ++_k) {
    const float2 e = myring[_k];
    if (e.x < A_kmax) { TS_INS(A_, e.x, __float_as_int(e.y)) }
  }

  // ---- R27 tail: branch-free sort + 4-way sorted merge ----
  __syncthreads();
  {
    SORT20
    float2* dumpw = (float2*)((wv & 2) ? (char*)Bbuf1 + (wv & 1) * 10752
                                       : (char*)Bbuf0 + (wv & 1) * 10752);
    float2* mydump = dumpw + lane * 21;
#define MG_DUMP(P, k) mydump[k] = make_float2(P##m##k, __int_as_float(P##p##k));
    REP20(MG_DUMP, A_)
#undef MG_DUMP
    const int srow = q * 16 + (c & 3);
    const float2* l0 = dumpw + (size_t)(srow + 0) * 21;
    const float2* l1 = dumpw + (size_t)(srow + 4) * 21;
    const float2* l2 = dumpw + (size_t)(srow + 8) * 21;
    const float2* l3 = dumpw + (size_t)(srow + 12) * 21;
    int c0 = 0, c1 = 0, c2 = 0, c3 = 0;
    float2 h0 = l0[0], h1 = l1[0], h2 = l2[0], h3 = l3[0];
    const size_t obase = (size_t)b * KNN * NN + isel;
    for (int k = 0; k < KNN; ++k) {
      const bool s01 =
          (h1.x < h0.x) ||
          ((h1.x == h0.x) && (__float_as_int(h1.y) < __float_as_int(h0.y)));
      const float2 m01 = s01 ? h1 : h0;
      const bool s23 =
          (h3.x < h2.x) ||
          ((h3.x == h2.x) && (__float_as_int(h3.y) < __float_as_int(h2.y)));
      const float2 m23 = s23 ? h3 : h2;
      const bool sF =
          (m23.x < m01.x) ||
          ((m23.x == m01.x) && (__float_as_int(m23.y) < __float_as_int(m01.y)));
      const float2 mm = sF ? m23 : m01;
      if (g == 0) idxf[obase + (size_t)k * NN] = __float_as_int(mm.y);
      const int w = sF ? (s23 ? 3 : 2) : (s01 ? 1 : 0);
      c0 += (w == 0); c1 += (w == 1); c2 += (w == 2); c3 += (w == 3);
      const float2 n0 = l0[c0], n1 = l1[c1], n2 = l2[c2], n3 = l3[c3];
      const float2 inf2 = make_float2(1e30f, __int_as_float(0x7fffffff));
      h0 = (c0 < KNN) ? n0 : inf2;
      h1 = (c1 < KNN) ? n1 : inf2;
      h2 = (c2 < KNN) ? n2 : inf2;
      h3 = (c3 < KNN) ? n3 : inf2;
    }
  }

  // ---- R30 tail: fused A/Q pass (former aq_kernel; A-frags still live) ----
  {
    unsigned short* Ab = Ab16 + (size_t)b * NN * OO;
    float* Qb = Q + (size_t)b * NN * OO;
#pragma unroll 2
    for (int ot = 0; ot < 8; ++ot) {
      const unsigned short* wrow = Wsp + (size_t)(ot * 16 + c) * WSPL + q * 8;
      const bf16x8 Ph0 = *(const bf16x8*)(wrow);
      const bf16x8 Ph1 = *(const bf16x8*)(wrow + 32);
      const bf16x8 Pm0 = *(const bf16x8*)(wrow + 128);
      const bf16x8 Pm1 = *(const bf16x8*)(wrow + 160);
      const bf16x8 Pl0 = *(const bf16x8*)(wrow + 256);
      const bf16x8 Pl1 = *(const bf16x8*)(wrow + 288);
      MFMA6(accP, Ph0, Ph1, Pm0, Pm1, Pl0, Pl1)
      const bf16x8 Gh0 = *(const bf16x8*)(wrow + 64);
      const bf16x8 Gh1 = *(const bf16x8*)(wrow + 96);
      const bf16x8 Gm0 = *(const bf16x8*)(wrow + 192);
      const bf16x8 Gm1 = *(const bf16x8*)(wrow + 224);
      const bf16x8 Gl0 = *(const bf16x8*)(wrow + 320);
      const bf16x8 Gl1 = *(const bf16x8*)(wrow + 352);
      MFMA6(accG, Gh0, Gh1, Gm0, Gm1, Gl0, Gl1)

      const float bv = bias[ot * 16 + c];
#pragma unroll
      for (int i = 0; i < 4; ++i) {
        const size_t row = (size_t)(ibase + q * 4 + i);
        const float p = accP[i];
        Ab[row * OO + ot * 16 + c] = (unsigned short)rne_bf16(p);
        Qb[row * OO + ot * 16 + c] = accG[i] - p + bv;
      }
    }
  }
}

// ---------------------------------------------------------------------------
// Kernel 4: gather + max + leaky + transposed store.
// R33: 512 thr/block, 2 rows/thread (40 scattered uint2 loads vs 80) --
// doubles outstanding-request parallelism to hide L2 latency.
// ---------------------------------------------------------------------------
__global__ __launch_bounds__(512) void gather_kernel(
    const unsigned short* __restrict__ Ab16, const float* __restrict__ Q,
    const int* __restrict__ idxf, float* __restrict__ out) {
  __shared__ int jidx[KNN][32];
  __shared__ float ob[32][OO + 1];

  const int b = blockIdx.y;
  const int n0 = blockIdx.x * 32;
  const int t = threadIdx.x;
  const int p = t & 31;   // channel quad: cols 4p..4p+3
  const int h = t >> 5;   // 0..15: rows 2h, 2h+1

  if (t < KNN * 32) {
    const int k = t >> 5, ii = t & 31;
    jidx[k][ii] = idxf[((size_t)b * KNN + k) * NN + n0 + ii];
  }
  if (t + 512 < KNN * 32) {
    const int e = t + 512;
    const int k = e >> 5, ii = e & 31;
    jidx[k][ii] = idxf[((size_t)b * KNN + k) * NN + n0 + ii];
  }
  __syncthreads();

  const unsigned short* Ab = Ab16 + (size_t)b * NN * OO;
  const float* Qb = Q + (size_t)b * NN * OO;

  for (int ii = h * 2; ii < h * 2 + 2; ++ii) {
    float m0 = -1e30f, m1 = -1e30f, m2 = -1e30f, m3 = -1e30f;
#pragma unroll
    for (int k = 0; k < KNN; ++k) {
      const uint2 v =
          *(const uint2*)(Ab + (size_t)jidx[k][ii] * OO + 4 * p);
      m0 = fmaxf(m0, __uint_as_float(v.x << 16));
      m1 = fmaxf(m1, __uint_as_float(v.x & 0xFFFF0000u));
      m2 = fmaxf(m2, __uint_as_float(v.y << 16));
      m3 = fmaxf(m3, __uint_as_float(v.y & 0xFFFF0000u));
    }
    const float4 qv = *(const float4*)(Qb + (size_t)(n0 + ii) * OO + 4 * p);
    const float h0 = m0 + qv.x;
    const float h1 = m1 + qv.y;
    const float h2 = m2 + qv.z;
    const float h3 = m3 + qv.w;
    ob[ii][4 * p + 0] = (h0 >= 0.f) ? h0 : 0.2f * h0;
    ob[ii][4 * p + 1] = (h1 >= 0.f) ? h1 : 0.2f * h1;
    ob[ii][4 * p + 2] = (h2 >= 0.f) ? h2 : 0.2f * h2;
    ob[ii][4 * p + 3] = (h3 >= 0.f) ? h3 : 0.2f * h3;
  }
  __syncthreads();

  float* ou = out + (size_t)b * OO * NN;
  for (int e = t; e < 32 * OO; e += 512) {
    const int ii = e & 31, oo = e >> 5;
    ou[(size_t)oo * NN + n0 + ii] = ob[ii][oo];
  }
}

// ---------------------------------------------------------------------------
extern "C" void kernel_launch(void* const* d_in, const int* in_sizes, int n_in,
                              void* d_out, int out_size, void* d_ws,
                              size_t ws_size, hipStream_t stream) {
  (void)in_sizes;
  (void)n_in;
  (void)out_size;
  (void)ws_size;
  const float* x = (const float*)d_in[0];
  const float* W = (const float*)d_in[1];
  const float* bias = (const float*)d_in[2];
  float* out = (float*)d_out;

  char* ws = (char*)d_ws;
  size_t off = 0;
  unsigned short* Ab16 = (unsigned short*)(ws + off);
  off += (size_t)BB * NN * OO * 2;              // 8 MB
  float* Q = (float*)(ws + off);
  off += (size_t)BB * NN * OO * 4;              // 16 MB
  float* xsq = (float*)(ws + off);
  off += (size_t)BB * NN * 4;                   // 128 KB
  unsigned short* xsp = (unsigned short*)(ws + off);
  off += (size_t)BB * NN * SPLITW * 2;          // 12.6 MB
  int* idxf = (int*)(ws + off);
  off += (size_t)BB * KNN * NN * 4;             // 2.6 MB
  unsigned short* Wsp = (unsigned short*)(ws + off);
  off += (size_t)OO * WSPL * 2;                 // 96 KB

  xprep_kernel<<<dim3(NN / 128, BB), 128, 0, stream>>>(x, W, xsq, xsp, Wsp);
  knn_kernel<<<dim3(NN / 64, BB), 256, 0, stream>>>(xsp, xsq, Wsp, bias,
                                                    Ab16, Q, idxf);
  gather_kernel<<<dim3(NN / 32, BB), 512, 0, stream>>>(Ab16, Q, idxf, out);
}